// Round 9
// baseline (422.172 us; speedup 1.0000x reference)
//
#include <hip/hip_runtime.h>

// MultiHeadedAttention, all-bf16-MFMA pipeline.
// prep (cast W, pack mask transposed) -> gemm<0> QKV (fp32 X reg-staged T14,
// W gload dbuf) -> attn (QBLK=64, 4 blocks/CU, log2 softmax) -> gemm<1>.
// B=2, S=4096, D_MODEL=512, NH=8, D_K=64.

#define S_LEN   4096
#define DM      512
#define NHEAD   8
#define DKH     64
#define NT      (S_LEN / 64)
#define LOG2E   1.44269504088896f
#define NEG2    (-1.44269504e9f)     // -1e9 * log2e (mask value, log2 domain)
#define MINIT   (-3.402823466e38f)
#define QSCALE  (0.125f * LOG2E)     // 1/sqrt(64) * log2e folded into Q

typedef __bf16 bf16x8 __attribute__((ext_vector_type(8)));
typedef __bf16 bf16x4 __attribute__((ext_vector_type(4)));
typedef float  f32x4  __attribute__((ext_vector_type(4)));
typedef unsigned long long u64;

#define F3(a,b,c) fmaxf(fmaxf((a),(b)),(c))

// native exp2: single TRANS op (v_exp_f32 computes 2^x)
__device__ inline float exp2fast(float x) {
    float r;
    asm("v_exp_f32 %0, %1" : "=v"(r) : "v"(x));
    return r;
}
// pack two f32 -> two bf16 in one op
__device__ inline unsigned cvtpk(float lo, float hi) {
    unsigned r;
    asm("v_cvt_pk_bf16_f32 %0, %1, %2" : "=v"(r) : "v"(lo), "v"(hi));
    return r;
}

// async global->LDS, 16B/lane; lds dest = wave-uniform base + lane*16
__device__ inline void gload_lds16(const void* g, void* l) {
    __builtin_amdgcn_global_load_lds(
        (const __attribute__((address_space(1))) unsigned int*)g,
        (__attribute__((address_space(3))) unsigned int*)l, 16, 0, 0);
}

__device__ inline uint4 cvt8(float4 a, float4 b) {
    uint4 u;
    u.x = cvtpk(a.x, a.y); u.y = cvtpk(a.z, a.w);
    u.z = cvtpk(b.x, b.y); u.w = cvtpk(b.z, b.w);
    return u;
}

// ---------------------------------------------------------------------------
// prep: blocks [0,512) cast W (4x512x512 fp32->bf16); [512,2560) pack mask
// into TRANSPOSED bit layout bits[(b*64 + kword)*4096 + row].
// ---------------------------------------------------------------------------
__global__ __launch_bounds__(256)
void prep(const int* __restrict__ mask,
          const float* __restrict__ Wq, const float* __restrict__ Wk,
          const float* __restrict__ Wv, const float* __restrict__ Wo,
          __bf16* __restrict__ wb, u64* __restrict__ bits)
{
    __shared__ u64 sm[4][64];
    const int blk = blockIdx.x, tid = threadIdx.x;

    if (blk < 512) {                       // ---- W cast ----
        const int t = blk * 256 + tid;
        const int e = t * 8, z = e >> 18, i = e & 262143;
        const float* W = (z == 0) ? Wq : (z == 1) ? Wk : (z == 2) ? Wv : Wo;
        const float4 a = *(const float4*)&W[i];
        const float4 b = *(const float4*)&W[i + 4];
        *(uint4*)&wb[e] = cvt8(a, b);
    } else {                               // ---- mask bitpack, transposed ----
        const int w4 = tid >> 6, lane = tid & 63;
        const int gw = (blk - 512) * 4 + w4;      // 0..8191
        const int p  = gw >> 6;                   // (b,kword) pair 0..127
        const int r0 = (gw & 63) << 6;            // row chunk base
        const int bb = p >> 6, wc = p & 63;
        #pragma unroll 4
        for (int it = 0; it < 64; ++it) {
            const int r = r0 + it;
            const size_t idx = (((size_t)(bb * S_LEN + r)) << 12) + (wc << 6) + lane;
            const u64 bal = __ballot(mask[idx] != 0);
            if (lane == 0) sm[w4][it] = bal;
        }
        bits[((size_t)p << 12) + r0 + lane] = sm[w4][lane];  // coalesced
    }
}

// ---------------------------------------------------------------------------
// bf16 MFMA GEMM (NT): Y[r,c] = sum_k X[r,k]*W[c,k]. Swapped operands:
// acc = mfma(A=Wfrag, B=Xfrag) -> lane holds row r=l15, 4 consecutive c.
// 512 thr = 8 waves, tile 128x128, BK=64, double-buffered.
// W via global_load_lds (pre-swizzled source), issued at step top.
// MODE 0: X fp32 -> T14 split: reg-load at step top, cvt+ds_write after
//         MFMAs (latency hidden under compute); out bf16 per-head scatter.
// MODE 1: X bf16 via global_load_lds; out fp32 row-major float4.
// ---------------------------------------------------------------------------
template<int MODE>
__global__ __launch_bounds__(512, 4)
void gemm_mfma(const float* __restrict__ X0, const float* __restrict__ X1,
               const float* __restrict__ X2, const __bf16* __restrict__ Xb,
               const __bf16* __restrict__ Wb,
               __bf16* __restrict__ Y0, __bf16* __restrict__ Y1,
               __bf16* __restrict__ Y2, float* __restrict__ Yf)
{
    __shared__ __align__(16) char lds[65536];   // [2][Xs 16K | Ws 16K]

    const int tid  = threadIdx.x;
    const int lane = tid & 63;
    const int l15  = lane & 15;
    const int lhi  = lane >> 4;
    const int w    = tid >> 6;
    const int wr   = w >> 2;
    const int wc   = w & 3;
    const int row0 = blockIdx.x << 7;
    const int col0 = blockIdx.y << 7;
    const int z    = blockIdx.z;

    const float*  Xf = (z == 0) ? X0 : (z == 1) ? X1 : X2;
    const __bf16* W  = Wb + (size_t)(MODE == 0 ? z : 3) * DM * DM;

    const int sr = tid >> 2;          // MODE0 X staging row
    const int sc = (tid & 3) << 1;    // slot pair

    f32x4 acc[4][2];
    #pragma unroll
    for (int m = 0; m < 4; ++m)
        #pragma unroll
        for (int n = 0; n < 2; ++n)
            acc[m][n] = (f32x4){0.f, 0.f, 0.f, 0.f};

    auto wstage = [&](int c, int k0) {        // W (and X if MODE1) async
        char* Xs = lds + c * 32768;
        char* Ws = Xs + 16384;
        #pragma unroll
        for (int s = 0; s < 2; ++s) {
            const int f = w * 128 + s * 64 + lane;
            const int r = f >> 3, sl = f & 7;
            const size_t go = (size_t)r * DM + k0 + ((sl ^ (r & 7)) << 3);
            if (MODE == 1)
                gload_lds16(&Xb[(size_t)row0 * DM + go], Xs + w * 2048 + s * 1024);
            gload_lds16(&W[(size_t)col0 * DM + go], Ws + w * 2048 + s * 1024);
        }
    };

    float4 xr0, xr1, xr2, xr3;
    auto xload = [&](int k0) {                // MODE0: fp32 X to regs
        const size_t base = (size_t)(row0 + sr) * DM + k0 + sc * 8;
        xr0 = *(const float4*)&Xf[base];
        xr1 = *(const float4*)&Xf[base + 4];
        xr2 = *(const float4*)&Xf[base + 8];
        xr3 = *(const float4*)&Xf[base + 12];
    };
    auto xwrite = [&](int c) {                // MODE0: cvt + ds_write
        char* Xs = lds + c * 32768;
        *(uint4*)(Xs + sr * 128 + ((sc       ^ (sr & 7)) << 4)) = cvt8(xr0, xr1);
        *(uint4*)(Xs + sr * 128 + (((sc + 1) ^ (sr & 7)) << 4)) = cvt8(xr2, xr3);
    };

    wstage(0, 0);
    if (MODE == 0) { xload(0); xwrite(0); }
    __syncthreads();

    for (int t = 0; t < 8; ++t) {
        const int c = t & 1;
        if (t < 7) {
            wstage(c ^ 1, (t + 1) * 64);      // lands during compute(t)
            if (MODE == 0) xload((t + 1) * 64);
        }

        const char* Xs = lds + c * 32768;
        const char* Ws = Xs + 16384;
        #pragma unroll
        for (int kk = 0; kk < 2; ++kk) {
            bf16x8 xf[4], wf[2];
            #pragma unroll
            for (int m = 0; m < 4; ++m) {
                const int r = wr * 64 + m * 16 + l15;
                xf[m] = *(const bf16x8*)(Xs + r * 128 + ((((kk << 2) + lhi) ^ (r & 7)) << 4));
            }
            #pragma unroll
            for (int n = 0; n < 2; ++n) {
                const int r = wc * 32 + n * 16 + l15;
                wf[n] = *(const bf16x8*)(Ws + r * 128 + ((((kk << 2) + lhi) ^ (r & 7)) << 4));
            }
            __builtin_amdgcn_s_setprio(1);
            #pragma unroll
            for (int m = 0; m < 4; ++m)
                #pragma unroll
                for (int n = 0; n < 2; ++n)
                    acc[m][n] = __builtin_amdgcn_mfma_f32_16x16x32_bf16(wf[n], xf[m], acc[m][n], 0, 0, 0);
            __builtin_amdgcn_s_setprio(0);
        }
        if (MODE == 0 && t < 7) xwrite(c ^ 1);   // after MFMAs: latency covered
        __syncthreads();   // drains vmcnt+lgkm: buf c^1 fully staged
    }

    // epilogue: lane -> row r, 4 consecutive out-channels
    const float osc = (MODE == 0 && z == 0) ? QSCALE : 1.0f;
    #pragma unroll
    for (int m = 0; m < 4; ++m) {
        const int r = row0 + wr * 64 + m * 16 + l15;
        #pragma unroll
        for (int n = 0; n < 2; ++n) {
            const int cb = col0 + wc * 32 + n * 16 + lhi * 4;
            if (MODE == 0) {
                bf16x4 o4;
                o4[0] = (__bf16)(acc[m][n][0] * osc);
                o4[1] = (__bf16)(acc[m][n][1] * osc);
                o4[2] = (__bf16)(acc[m][n][2] * osc);
                o4[3] = (__bf16)(acc[m][n][3] * osc);
                const int bb = r >> 12, srow = r & 4095;
                const int hh = cb >> 6, dk = cb & 63;
                __bf16* Yb = (z == 0) ? Y0 : (z == 1) ? Y1 : Y2;
                *(bf16x4*)&Yb[(((size_t)(bb * NHEAD + hh)) * S_LEN + srow) * DKH + dk] = o4;
            } else {
                *(float4*)&Yf[(size_t)r * DM + cb] = *(float4*)&acc[m][n];
            }
        }
    }
}

// ---------------------------------------------------------------------------
// Flash attention: QBLK=64 (256 thr = 4 waves), 4 blocks/CU for barrier
// overlap. Swapped-operand MFMA, in-register log2 softmax (v_exp_f32,
// cvt_pk), dbuf K/V, one barrier/tile.
// LDS 40KB: [buf0: Ks 8K | Vt 8K][buf1: Ks | Vt][Ps 4x2K wave-private].
// ---------------------------------------------------------------------------
__global__ __launch_bounds__(256, 4)
void attn_mfma(const __bf16* __restrict__ Q, const __bf16* __restrict__ K,
               const __bf16* __restrict__ V, const u64* __restrict__ bits,
               __bf16* __restrict__ ctx)
{
    __shared__ __align__(16) char lds[40960];

    const int tid  = threadIdx.x;
    const int lane = tid & 63;
    const int w    = tid >> 6;          // wave 0..3
    const int l15  = lane & 15;
    const int lhi  = lane >> 4;
    const int q0   = blockIdx.x << 6;
    const int h    = blockIdx.y;
    const int b    = blockIdx.z;

    const __bf16* Qb = Q + (size_t)(b * NHEAD + h) * S_LEN * DKH;
    const __bf16* Kb = K + (size_t)(b * NHEAD + h) * S_LEN * DKH;
    const __bf16* Vb = V + (size_t)(b * NHEAD + h) * S_LEN * DKH;

    const int qrow = q0 + w * 16 + l15;
    // transposed bit layout: word(kt) at bits[(b*64+kt)*4096 + qrow]
    const u64* Mb = bits + ((size_t)b << 18) + qrow;

    const bf16x8 qa0 = *(const bf16x8*)&Qb[(size_t)qrow * DKH + lhi * 8];
    const bf16x8 qa1 = *(const bf16x8*)&Qb[(size_t)qrow * DKH + 32 + lhi * 8];

    char* psb = lds + 32768 + w * 2048;    // wave-private P scratch

    f32x4 o[4];
    float m_r = MINIT, l_r = 0.f;
    #pragma unroll
    for (int dt = 0; dt < 4; ++dt) o[dt] = (f32x4){0.f, 0.f, 0.f, 0.f};

    // K staging: 2 segments/thread. idx = s*256+tid -> row idx>>3, slot idx&7
    const int kr0 = tid >> 3, ks0 = tid & 7;          // s=0: rows 0..31
    const int kr1 = kr0 + 32, ks1 = ks0;              // s=1: rows 32..63
    // V staging: vj = tid&63 source row; two d-halves vd0, vd0+32
    const int vj = tid & 63, vd0 = (tid >> 6) * 8;

    auto kstage = [&](int c, int j0) {
        gload_lds16(&Kb[(size_t)(j0 + kr0) * DKH + ((ks0 ^ (kr0 & 7)) << 3)],
                    lds + c * 16384 + w * 1024);
        gload_lds16(&Kb[(size_t)(j0 + kr1) * DKH + ((ks1 ^ (kr1 & 7)) << 3)],
                    lds + c * 16384 + 4096 + w * 1024);
    };
    auto vwrite = [&](int c, uint4 va, uint4 vb2) {
        char* Vt = lds + c * 16384 + 8192;
        const __bf16* ra = (const __bf16*)&va;
        const __bf16* rb = (const __bf16*)&vb2;
        #pragma unroll
        for (int i = 0; i < 8; ++i) {
            const int d1 = vd0 + i, d2 = vd0 + 32 + i;
            *(__bf16*)(Vt + ((d1 * 128 + vj * 2) ^ ((d1 & 7) << 4))) = ra[i];
            *(__bf16*)(Vt + ((d2 * 128 + vj * 2) ^ ((d2 & 7) << 4))) = rb[i];
        }
    };

    // prologue: stage tile 0 into buffer 0
    kstage(0, 0);
    vwrite(0, *(const uint4*)&Vb[(size_t)vj * DKH + vd0],
              *(const uint4*)&Vb[(size_t)vj * DKH + vd0 + 32]);
    u64 mcur = Mb[0];
    __syncthreads();

    for (int t = 0; t < NT; ++t) {
        const int c  = t & 1;
        const int tn = (t + 1 < NT) ? (t + 1) : t;

        // issue next tile's loads now; they land during this tile's compute
        kstage(c ^ 1, tn << 6);
        const uint4 vna = *(const uint4*)&Vb[(size_t)((tn << 6) + vj) * DKH + vd0];
        const uint4 vnb = *(const uint4*)&Vb[(size_t)((tn << 6) + vj) * DKH + vd0 + 32];
        const u64   mnxt = Mb[(size_t)tn << 12];

        const char* Ksb = lds + c * 16384;
        const char* Vtb = Ksb + 8192;

        // ---- QK^T (swapped): s[tt] rows tt*16..+15 of S^T, col q=l15 ----
        f32x4 s[4];
        __builtin_amdgcn_s_setprio(1);
        #pragma unroll
        for (int tt = 0; tt < 4; ++tt) {
            const int kr  = tt * 16 + l15;
            const int off = kr * 128 + ((lhi ^ (kr & 7)) << 4);
            const bf16x8 kb0 = *(const bf16x8*)(Ksb + off);
            const bf16x8 kb1 = *(const bf16x8*)(Ksb + (off ^ 64));
            f32x4 zz = (f32x4){0.f, 0.f, 0.f, 0.f};
            zz    = __builtin_amdgcn_mfma_f32_16x16x32_bf16(kb0, qa0, zz, 0, 0, 0);
            s[tt] = __builtin_amdgcn_mfma_f32_16x16x32_bf16(kb1, qa1, zz, 0, 0, 0);
        }
        __builtin_amdgcn_s_setprio(0);

        // ---- mask + in-register online softmax (log2 domain) ----
        const unsigned int lo = (unsigned int)mcur, hi = (unsigned int)(mcur >> 32);
        unsigned int shf[4];
        shf[0] = lo >> (lhi << 2);
        shf[1] = lo >> (16 + (lhi << 2));
        shf[2] = hi >> (lhi << 2);
        shf[3] = hi >> (16 + (lhi << 2));

        float pv[4][4];
        #pragma unroll
        for (int tt = 0; tt < 4; ++tt)
            #pragma unroll
            for (int r = 0; r < 4; ++r)
                pv[tt][r] = ((shf[tt] >> r) & 1) ? NEG2 : s[tt][r];

        float a0 = F3(pv[0][0], pv[0][1], pv[0][2]);
        float a1 = F3(pv[0][3], pv[1][0], pv[1][1]);
        float a2 = F3(pv[1][2], pv[1][3], pv[2][0]);
        float a3 = F3(pv[2][1], pv[2][2], pv[2][3]);
        float a4 = F3(pv[3][0], pv[3][1], pv[3][2]);
        float tmax = fmaxf(F3(a0, a1, a2), F3(a3, a4, pv[3][3]));
        tmax = fmaxf(tmax, __shfl_xor(tmax, 16));
        tmax = fmaxf(tmax, __shfl_xor(tmax, 32));

        if (!__all(tmax <= m_r + 8.f)) {   // defer-max (T13), log2 units
            const float newm  = fmaxf(m_r, tmax);
            const float alpha = exp2fast(m_r - newm);
            m_r = newm;
            l_r *= alpha;
            #pragma unroll
            for (int dt = 0; dt < 4; ++dt) {
                o[dt][0] *= alpha; o[dt][1] *= alpha;
                o[dt][2] *= alpha; o[dt][3] *= alpha;
            }
        }

        float rsum = 0.f;
        #pragma unroll
        for (int tt = 0; tt < 4; ++tt)
            #pragma unroll
            for (int r = 0; r < 4; ++r) {
                pv[tt][r] = exp2fast(pv[tt][r] - m_r);
                rsum += pv[tt][r];
            }
        rsum += __shfl_xor(rsum, 16);
        rsum += __shfl_xor(rsum, 32);
        l_r += rsum;

        // ---- P -> bf16 via cvt_pk, wave-private LDS, b64 writes ----
        #pragma unroll
        for (int tt = 0; tt < 4; ++tt) {
            uint2 pk;
            pk.x = cvtpk(pv[tt][0], pv[tt][1]);
            pk.y = cvtpk(pv[tt][2], pv[tt][3]);
            const int off = l15 * 128
                          + ((((tt << 1) + (lhi >> 1)) ^ (l15 & 7)) << 4)
                          + ((lhi & 1) << 3);
            *(uint2*)(psb + off) = pk;
        }
        const int poff = l15 * 128 + ((lhi ^ (l15 & 7)) << 4);
        const bf16x8 pb0 = *(const bf16x8*)(psb + poff);
        const bf16x8 pb1 = *(const bf16x8*)(psb + (poff ^ 64));

        // ---- PV (swapped): o[dt] rows d=dt*16..+15 of O^T, col q=l15 ----
        __builtin_amdgcn_s_setprio(1);
        #pragma unroll
        for (int dt = 0; dt < 4; ++dt) {
            const int vrow = dt * 16 + l15;
            const int voff = vrow * 128 + ((lhi ^ (vrow & 7)) << 4);
            const bf16x8 vb0 = *(const bf16x8*)(Vtb + voff);
            const bf16x8 vb1 = *(const bf16x8*)(Vtb + (voff ^ 64));
            o[dt] = __builtin_amdgcn_mfma_f32_16x16x32_bf16(vb0, pb0, o[dt], 0, 0, 0);
            o[dt] = __builtin_amdgcn_mfma_f32_16x16x32_bf16(vb1, pb1, o[dt], 0, 0, 0);
        }
        __builtin_amdgcn_s_setprio(0);

        // ---- stage V(t+1) into the other buffer; single barrier ----
        vwrite(c ^ 1, vna, vnb);
        __syncthreads();   // drains vmcnt+lgkm: next tile fully staged
        mcur = mnxt;
    }

    // epilogue: O^T[q=l15][d=dt*16+lhi*4+r] -> ctx bf16 [B,S,512]
    const float inv = 1.f / l_r;
    #pragma unroll
    for (int dt = 0; dt < 4; ++dt) {
        bf16x4 ov;
        ov[0] = (__bf16)(o[dt][0] * inv);
        ov[1] = (__bf16)(o[dt][1] * inv);
        ov[2] = (__bf16)(o[dt][2] * inv);
        ov[3] = (__bf16)(o[dt][3] * inv);
        *(bf16x4*)&ctx[((size_t)b * S_LEN + qrow) * DM + h * DKH + dt * 16 + lhi * 4] = ov;
    }
}

// ---------------------------------------------------------------------------
extern "C" void kernel_launch(void* const* d_in, const int* in_sizes, int n_in,
                              void* d_out, int out_size, void* d_ws, size_t ws_size,
                              hipStream_t stream)
{
    const float* q    = (const float*)d_in[0];
    const float* k    = (const float*)d_in[1];
    const float* v    = (const float*)d_in[2];
    const int*   mask = (const int*)d_in[3];
    const float* Wq   = (const float*)d_in[4];
    const float* Wk   = (const float*)d_in[5];
    const float* Wv   = (const float*)d_in[6];
    const float* Wo   = (const float*)d_in[7];
    float* out = (float*)d_out;

    // ws: wb 2MB | Qh|Kh|Vh|ctx 8.39MB each | bits 4.2MB = ~40MB
    const size_t per = (size_t)2 * S_LEN * DM;          // 4,194,304
    __bf16* wb   = (__bf16*)d_ws;
    __bf16* Qh   = wb + (size_t)4 * DM * DM;
    __bf16* Kh   = Qh + per;
    __bf16* Vh   = Kh + per;
    __bf16* ctx  = Vh + per;
    u64*    bits = (u64*)(ctx + per);

    prep<<<dim3(2560), dim3(256), 0, stream>>>(mask, Wq, Wk, Wv, Wo, wb, bits);

    gemm_mfma<0><<<dim3(64, 4, 3), dim3(512), 0, stream>>>(
        q, k, v, nullptr, wb, Qh, Kh, Vh, nullptr);

    attn_mfma<<<dim3(64, 8, 2), dim3(256), 0, stream>>>(Qh, Kh, Vh, bits, ctx);

    gemm_mfma<1><<<dim3(64, 4, 1), dim3(512), 0, stream>>>(
        nullptr, nullptr, nullptr, ctx, wb, nullptr, nullptr, nullptr, out);
}

// Round 10
// 394.625 us; speedup vs baseline: 1.0698x; 1.0698x over previous
//
#include <hip/hip_runtime.h>

// MultiHeadedAttention, all-bf16-MFMA pipeline.
// prep (cast W, pack mask transposed) -> gemm<0> QKV (V written TRANSPOSED)
// -> attn (K and V^T both via async global_load_lds, dbuf, 1 barrier/tile,
// log2 softmax, 144B-stride Ps) -> gemm<1> out proj.
// B=2, S=4096, D_MODEL=512, NH=8, D_K=64.

#define S_LEN   4096
#define DM      512
#define NHEAD   8
#define DKH     64
#define NT      (S_LEN / 64)
#define LOG2E   1.44269504088896f
#define NEG2    (-1.44269504e9f)     // -1e9 * log2e (mask value, log2 domain)
#define MINIT   (-3.402823466e38f)
#define QSCALE  (0.125f * LOG2E)     // 1/sqrt(64) * log2e folded into Q

typedef __bf16 bf16x8 __attribute__((ext_vector_type(8)));
typedef __bf16 bf16x4 __attribute__((ext_vector_type(4)));
typedef float  f32x4  __attribute__((ext_vector_type(4)));
typedef unsigned long long u64;

#define F3(a,b,c) fmaxf(fmaxf((a),(b)),(c))

// native exp2: single TRANS op (v_exp_f32 computes 2^x)
__device__ inline float exp2fast(float x) {
    float r;
    asm("v_exp_f32 %0, %1" : "=v"(r) : "v"(x));
    return r;
}
// pack two f32 -> two bf16 in one op
__device__ inline unsigned cvtpk(float lo, float hi) {
    unsigned r;
    asm("v_cvt_pk_bf16_f32 %0, %1, %2" : "=v"(r) : "v"(lo), "v"(hi));
    return r;
}

// async global->LDS, 16B/lane; lds dest = wave-uniform base + lane*16
__device__ inline void gload_lds16(const void* g, void* l) {
    __builtin_amdgcn_global_load_lds(
        (const __attribute__((address_space(1))) unsigned int*)g,
        (__attribute__((address_space(3))) unsigned int*)l, 16, 0, 0);
}

__device__ inline uint4 cvt8(float4 a, float4 b) {
    uint4 u;
    u.x = cvtpk(a.x, a.y); u.y = cvtpk(a.z, a.w);
    u.z = cvtpk(b.x, b.y); u.w = cvtpk(b.z, b.w);
    return u;
}

// ---------------------------------------------------------------------------
// prep: blocks [0,512) cast W (4x512x512 fp32->bf16); [512,2560) pack mask
// into TRANSPOSED bit layout bits[(b*64 + kword)*4096 + row].
// ---------------------------------------------------------------------------
__global__ __launch_bounds__(256)
void prep(const int* __restrict__ mask,
          const float* __restrict__ Wq, const float* __restrict__ Wk,
          const float* __restrict__ Wv, const float* __restrict__ Wo,
          __bf16* __restrict__ wb, u64* __restrict__ bits)
{
    __shared__ u64 sm[4][64];
    const int blk = blockIdx.x, tid = threadIdx.x;

    if (blk < 512) {                       // ---- W cast ----
        const int t = blk * 256 + tid;
        const int e = t * 8, z = e >> 18, i = e & 262143;
        const float* W = (z == 0) ? Wq : (z == 1) ? Wk : (z == 2) ? Wv : Wo;
        const float4 a = *(const float4*)&W[i];
        const float4 b = *(const float4*)&W[i + 4];
        *(uint4*)&wb[e] = cvt8(a, b);
    } else {                               // ---- mask bitpack, transposed ----
        const int w4 = tid >> 6, lane = tid & 63;
        const int gw = (blk - 512) * 4 + w4;      // 0..8191
        const int p  = gw >> 6;                   // (b,kword) pair 0..127
        const int r0 = (gw & 63) << 6;            // row chunk base
        const int bb = p >> 6, wc = p & 63;
        #pragma unroll 4
        for (int it = 0; it < 64; ++it) {
            const int r = r0 + it;
            const size_t idx = (((size_t)(bb * S_LEN + r)) << 12) + (wc << 6) + lane;
            const u64 bal = __ballot(mask[idx] != 0);
            if (lane == 0) sm[w4][it] = bal;
        }
        bits[((size_t)p << 12) + r0 + lane] = sm[w4][lane];  // coalesced
    }
}

// ---------------------------------------------------------------------------
// bf16 MFMA GEMM (NT): Y[r,c] = sum_k X[r,k]*W[c,k]. Swapped operands:
// acc = mfma(A=Wfrag, B=Xfrag) -> lane holds row r=l15, 4 consecutive c.
// 512 thr = 8 waves, tile 128x128, BK=64, double-buffered; W via
// global_load_lds (pre-swizzled source) issued at step top.
// MODE 0: X fp32 reg-staged (T14: load at top, cvt+ds_write after MFMAs);
//         out bf16 per-head scatter. z==0 folds QSCALE; z==2 (V) writes
//         TRANSPOSED VhT[b][h][d][s] so attn can async-stage V^T.
// MODE 1: X bf16 via global_load_lds; out fp32 row-major float4.
// ---------------------------------------------------------------------------
template<int MODE>
__global__ __launch_bounds__(512, 4)
void gemm_mfma(const float* __restrict__ X0, const float* __restrict__ X1,
               const float* __restrict__ X2, const __bf16* __restrict__ Xb,
               const __bf16* __restrict__ Wb,
               __bf16* __restrict__ Y0, __bf16* __restrict__ Y1,
               __bf16* __restrict__ Y2, float* __restrict__ Yf)
{
    __shared__ __align__(16) char lds[65536];   // [2][Xs 16K | Ws 16K]

    const int tid  = threadIdx.x;
    const int lane = tid & 63;
    const int l15  = lane & 15;
    const int lhi  = lane >> 4;
    const int w    = tid >> 6;
    const int wr   = w >> 2;
    const int wc   = w & 3;
    const int row0 = blockIdx.x << 7;
    const int col0 = blockIdx.y << 7;
    const int z    = blockIdx.z;

    const float*  Xf = (z == 0) ? X0 : (z == 1) ? X1 : X2;
    const __bf16* W  = Wb + (size_t)(MODE == 0 ? z : 3) * DM * DM;

    const int sr = tid >> 2;          // MODE0 X staging row
    const int sc = (tid & 3) << 1;    // slot pair

    f32x4 acc[4][2];
    #pragma unroll
    for (int m = 0; m < 4; ++m)
        #pragma unroll
        for (int n = 0; n < 2; ++n)
            acc[m][n] = (f32x4){0.f, 0.f, 0.f, 0.f};

    auto wstage = [&](int c, int k0) {        // W (and X if MODE1) async
        char* Xs = lds + c * 32768;
        char* Ws = Xs + 16384;
        #pragma unroll
        for (int s = 0; s < 2; ++s) {
            const int f = w * 128 + s * 64 + lane;
            const int r = f >> 3, sl = f & 7;
            const size_t go = (size_t)r * DM + k0 + ((sl ^ (r & 7)) << 3);
            if (MODE == 1)
                gload_lds16(&Xb[(size_t)row0 * DM + go], Xs + w * 2048 + s * 1024);
            gload_lds16(&W[(size_t)col0 * DM + go], Ws + w * 2048 + s * 1024);
        }
    };

    float4 xr0, xr1, xr2, xr3;
    auto xload = [&](int k0) {                // MODE0: fp32 X to regs
        const size_t base = (size_t)(row0 + sr) * DM + k0 + sc * 8;
        xr0 = *(const float4*)&Xf[base];
        xr1 = *(const float4*)&Xf[base + 4];
        xr2 = *(const float4*)&Xf[base + 8];
        xr3 = *(const float4*)&Xf[base + 12];
    };
    auto xwrite = [&](int c) {                // MODE0: cvt + ds_write
        char* Xs = lds + c * 32768;
        *(uint4*)(Xs + sr * 128 + ((sc       ^ (sr & 7)) << 4)) = cvt8(xr0, xr1);
        *(uint4*)(Xs + sr * 128 + (((sc + 1) ^ (sr & 7)) << 4)) = cvt8(xr2, xr3);
    };

    wstage(0, 0);
    if (MODE == 0) { xload(0); xwrite(0); }
    __syncthreads();

    for (int t = 0; t < 8; ++t) {
        const int c = t & 1;
        if (t < 7) {
            wstage(c ^ 1, (t + 1) * 64);      // lands during compute(t)
            if (MODE == 0) xload((t + 1) * 64);
        }

        const char* Xs = lds + c * 32768;
        const char* Ws = Xs + 16384;
        #pragma unroll
        for (int kk = 0; kk < 2; ++kk) {
            bf16x8 xf[4], wf[2];
            #pragma unroll
            for (int m = 0; m < 4; ++m) {
                const int r = wr * 64 + m * 16 + l15;
                xf[m] = *(const bf16x8*)(Xs + r * 128 + ((((kk << 2) + lhi) ^ (r & 7)) << 4));
            }
            #pragma unroll
            for (int n = 0; n < 2; ++n) {
                const int r = wc * 32 + n * 16 + l15;
                wf[n] = *(const bf16x8*)(Ws + r * 128 + ((((kk << 2) + lhi) ^ (r & 7)) << 4));
            }
            __builtin_amdgcn_s_setprio(1);
            #pragma unroll
            for (int m = 0; m < 4; ++m)
                #pragma unroll
                for (int n = 0; n < 2; ++n)
                    acc[m][n] = __builtin_amdgcn_mfma_f32_16x16x32_bf16(wf[n], xf[m], acc[m][n], 0, 0, 0);
            __builtin_amdgcn_s_setprio(0);
        }
        if (MODE == 0 && t < 7) xwrite(c ^ 1);   // after MFMAs: latency covered
        __syncthreads();   // drains vmcnt+lgkm: buf c^1 fully staged
    }

    // epilogue: lane -> row r, 4 consecutive out-channels
    const float osc = (MODE == 0 && z == 0) ? QSCALE : 1.0f;
    #pragma unroll
    for (int m = 0; m < 4; ++m) {
        const int r = row0 + wr * 64 + m * 16 + l15;
        #pragma unroll
        for (int n = 0; n < 2; ++n) {
            const int cb = col0 + wc * 32 + n * 16 + lhi * 4;
            if (MODE == 0) {
                const int bb = r >> 12, srow = r & 4095;
                const int hh = cb >> 6, dk = cb & 63;
                if (z == 2) {
                    // V transposed: VhT[((b*NH+h)*64 + d)*4096 + s]
                    #pragma unroll
                    for (int i = 0; i < 4; ++i)
                        Y2[(((size_t)(bb * NHEAD + hh)) * DKH + dk + i) * S_LEN + srow] =
                            (__bf16)acc[m][n][i];
                } else {
                    bf16x4 o4;
                    o4[0] = (__bf16)(acc[m][n][0] * osc);
                    o4[1] = (__bf16)(acc[m][n][1] * osc);
                    o4[2] = (__bf16)(acc[m][n][2] * osc);
                    o4[3] = (__bf16)(acc[m][n][3] * osc);
                    __bf16* Yb = (z == 0) ? Y0 : Y1;
                    *(bf16x4*)&Yb[(((size_t)(bb * NHEAD + hh)) * S_LEN + srow) * DKH + dk] = o4;
                }
            } else {
                *(float4*)&Yf[(size_t)r * DM + cb] = *(float4*)&acc[m][n];
            }
        }
    }
}

// ---------------------------------------------------------------------------
// Flash attention: swapped-operand MFMA, in-register log2 softmax, K and V^T
// both staged via async global_load_lds (pre-swizzled sources), dbuf,
// ONE barrier/tile. 512 thr = 8 waves, 128 q-rows/block.
// LDS 50KB: [buf0: Ks 8K | Vt 8K][buf1][Ps 8 x 2304B, 144B row stride
// (bank-group = (row+slot) mod 8 -> conflict-free reads)].
// ---------------------------------------------------------------------------
__global__ __launch_bounds__(512, 4)
void attn_mfma(const __bf16* __restrict__ Q, const __bf16* __restrict__ K,
               const __bf16* __restrict__ VT, const u64* __restrict__ bits,
               __bf16* __restrict__ ctx)
{
    __shared__ __align__(16) char lds[51200];

    const int tid  = threadIdx.x;
    const int lane = tid & 63;
    const int w    = tid >> 6;
    const int l15  = lane & 15;
    const int lhi  = lane >> 4;
    const int q0   = blockIdx.x << 7;
    const int h    = blockIdx.y;
    const int b    = blockIdx.z;

    const __bf16* Qb  = Q  + (size_t)(b * NHEAD + h) * S_LEN * DKH;
    const __bf16* Kb  = K  + (size_t)(b * NHEAD + h) * S_LEN * DKH;
    const __bf16* VbT = VT + (size_t)(b * NHEAD + h) * DKH * S_LEN;  // [64 d][4096 s]

    const int qrow = q0 + w * 16 + l15;
    // transposed bit layout: word(kt) at bits[(b*64+kt)*4096 + qrow]
    const u64* Mb = bits + ((size_t)b << 18) + qrow;

    const bf16x8 qa0 = *(const bf16x8*)&Qb[(size_t)qrow * DKH + lhi * 8];
    const bf16x8 qa1 = *(const bf16x8*)&Qb[(size_t)qrow * DKH + 32 + lhi * 8];

    char* psb = lds + 32768 + w * 2304;    // wave-private P scratch, 144B rows

    f32x4 o[4];
    float m_r = MINIT, l_r = 0.f;
    #pragma unroll
    for (int dt = 0; dt < 4; ++dt) o[dt] = (f32x4){0.f, 0.f, 0.f, 0.f};

    // staging maps (both pure gload_lds, 1 each per thread per tile)
    const int krow = tid >> 3, kslot = tid & 7;   // K: row j, 16B slot
    const int vrow_ = krow, vslot = kslot;        // V^T: row d, 16B slot (j-seg)

    auto kstage = [&](int c, int j0) {
        gload_lds16(&Kb[(size_t)(j0 + krow) * DKH + ((kslot ^ (krow & 7)) << 3)],
                    lds + c * 16384 + w * 1024);
    };
    auto vstage = [&](int c, int j0) {
        gload_lds16(&VbT[(size_t)vrow_ * S_LEN + j0 + ((vslot ^ (vrow_ & 7)) << 3)],
                    lds + c * 16384 + 8192 + w * 1024);
    };

    // prologue: stage tile 0 into buffer 0
    kstage(0, 0);
    vstage(0, 0);
    u64 mcur = Mb[0];
    __syncthreads();

    for (int t = 0; t < NT; ++t) {
        const int c  = t & 1;
        const int tn = (t + 1 < NT) ? (t + 1) : t;

        // issue next tile's async loads; they land during this tile's compute
        kstage(c ^ 1, tn << 6);
        vstage(c ^ 1, tn << 6);
        const u64 mnxt = Mb[(size_t)tn << 12];

        const char* Ksb = lds + c * 16384;
        const char* Vtb = Ksb + 8192;

        // ---- QK^T (swapped): s[tt] rows tt*16..+15 of S^T, col q=l15 ----
        f32x4 s[4];
        __builtin_amdgcn_s_setprio(1);
        #pragma unroll
        for (int tt = 0; tt < 4; ++tt) {
            const int kr  = tt * 16 + l15;
            const int off = kr * 128 + ((lhi ^ (kr & 7)) << 4);
            const bf16x8 kb0 = *(const bf16x8*)(Ksb + off);
            const bf16x8 kb1 = *(const bf16x8*)(Ksb + (off ^ 64));
            f32x4 zz = (f32x4){0.f, 0.f, 0.f, 0.f};
            zz    = __builtin_amdgcn_mfma_f32_16x16x32_bf16(kb0, qa0, zz, 0, 0, 0);
            s[tt] = __builtin_amdgcn_mfma_f32_16x16x32_bf16(kb1, qa1, zz, 0, 0, 0);
        }
        __builtin_amdgcn_s_setprio(0);

        // ---- mask + in-register online softmax (log2 domain) ----
        const unsigned int lo = (unsigned int)mcur, hi = (unsigned int)(mcur >> 32);
        unsigned int shf[4];
        shf[0] = lo >> (lhi << 2);
        shf[1] = lo >> (16 + (lhi << 2));
        shf[2] = hi >> (lhi << 2);
        shf[3] = hi >> (16 + (lhi << 2));

        float pv[4][4];
        #pragma unroll
        for (int tt = 0; tt < 4; ++tt)
            #pragma unroll
            for (int r = 0; r < 4; ++r)
                pv[tt][r] = ((shf[tt] >> r) & 1) ? NEG2 : s[tt][r];

        float a0 = F3(pv[0][0], pv[0][1], pv[0][2]);
        float a1 = F3(pv[0][3], pv[1][0], pv[1][1]);
        float a2 = F3(pv[1][2], pv[1][3], pv[2][0]);
        float a3 = F3(pv[2][1], pv[2][2], pv[2][3]);
        float a4 = F3(pv[3][0], pv[3][1], pv[3][2]);
        float tmax = fmaxf(F3(a0, a1, a2), F3(a3, a4, pv[3][3]));
        tmax = fmaxf(tmax, __shfl_xor(tmax, 16));
        tmax = fmaxf(tmax, __shfl_xor(tmax, 32));

        if (!__all(tmax <= m_r + 8.f)) {   // defer-max (T13), log2 units
            const float newm  = fmaxf(m_r, tmax);
            const float alpha = exp2fast(m_r - newm);
            m_r = newm;
            l_r *= alpha;
            #pragma unroll
            for (int dt = 0; dt < 4; ++dt) {
                o[dt][0] *= alpha; o[dt][1] *= alpha;
                o[dt][2] *= alpha; o[dt][3] *= alpha;
            }
        }

        float rsum = 0.f;
        #pragma unroll
        for (int tt = 0; tt < 4; ++tt)
            #pragma unroll
            for (int r = 0; r < 4; ++r) {
                pv[tt][r] = exp2fast(pv[tt][r] - m_r);
                rsum += pv[tt][r];
            }
        rsum += __shfl_xor(rsum, 16);
        rsum += __shfl_xor(rsum, 32);
        l_r += rsum;

        // ---- P -> bf16 via cvt_pk; 144B-stride rows, linear k layout ----
        #pragma unroll
        for (int tt = 0; tt < 4; ++tt) {
            uint2 pk;
            pk.x = cvtpk(pv[tt][0], pv[tt][1]);
            pk.y = cvtpk(pv[tt][2], pv[tt][3]);
            // dwords 8tt+2lhi, +1  ->  byte = ((tt<<1)+(lhi>>1))*16 + (lhi&1)*8
            const int off = l15 * 144 + (((tt << 1) + (lhi >> 1)) << 4)
                          + ((lhi & 1) << 3);
            *(uint2*)(psb + off) = pk;
        }
        const int poff = l15 * 144 + (lhi << 4);
        const bf16x8 pb0 = *(const bf16x8*)(psb + poff);        // k =  8*lhi..
        const bf16x8 pb1 = *(const bf16x8*)(psb + poff + 64);   // k = 32+8*lhi..

        // ---- PV (swapped): o[dt] rows d=dt*16..+15 of O^T, col q=l15 ----
        __builtin_amdgcn_s_setprio(1);
        #pragma unroll
        for (int dt = 0; dt < 4; ++dt) {
            const int vr  = dt * 16 + l15;
            const int voff = vr * 128 + ((lhi ^ (vr & 7)) << 4);
            const bf16x8 vb0 = *(const bf16x8*)(Vtb + voff);
            const bf16x8 vb1 = *(const bf16x8*)(Vtb + (voff ^ 64));
            o[dt] = __builtin_amdgcn_mfma_f32_16x16x32_bf16(vb0, pb0, o[dt], 0, 0, 0);
            o[dt] = __builtin_amdgcn_mfma_f32_16x16x32_bf16(vb1, pb1, o[dt], 0, 0, 0);
        }
        __builtin_amdgcn_s_setprio(0);

        __syncthreads();   // drains vmcnt+lgkm: next tile fully staged
        mcur = mnxt;
    }

    // epilogue: O^T[q=l15][d=dt*16+lhi*4+r] -> ctx bf16 [B,S,512]
    const float inv = 1.f / l_r;
    #pragma unroll
    for (int dt = 0; dt < 4; ++dt) {
        bf16x4 ov;
        ov[0] = (__bf16)(o[dt][0] * inv);
        ov[1] = (__bf16)(o[dt][1] * inv);
        ov[2] = (__bf16)(o[dt][2] * inv);
        ov[3] = (__bf16)(o[dt][3] * inv);
        *(bf16x4*)&ctx[((size_t)b * S_LEN + qrow) * DM + h * DKH + dt * 16 + lhi * 4] = ov;
    }
}

// ---------------------------------------------------------------------------
extern "C" void kernel_launch(void* const* d_in, const int* in_sizes, int n_in,
                              void* d_out, int out_size, void* d_ws, size_t ws_size,
                              hipStream_t stream)
{
    const float* q    = (const float*)d_in[0];
    const float* k    = (const float*)d_in[1];
    const float* v    = (const float*)d_in[2];
    const int*   mask = (const int*)d_in[3];
    const float* Wq   = (const float*)d_in[4];
    const float* Wk   = (const float*)d_in[5];
    const float* Wv   = (const float*)d_in[6];
    const float* Wo   = (const float*)d_in[7];
    float* out = (float*)d_out;

    // ws: wb 2MB | Qh|Kh|VhT|ctx 8.39MB each | bits 4.2MB = ~40MB
    const size_t per = (size_t)2 * S_LEN * DM;          // 4,194,304
    __bf16* wb   = (__bf16*)d_ws;
    __bf16* Qh   = wb + (size_t)4 * DM * DM;
    __bf16* Kh   = Qh + per;
    __bf16* VhT  = Kh + per;     // transposed: [b][h][64 d][4096 s]
    __bf16* ctx  = VhT + per;
    u64*    bits = (u64*)(ctx + per);

    prep<<<dim3(2560), dim3(256), 0, stream>>>(mask, Wq, Wk, Wv, Wo, wb, bits);

    gemm_mfma<0><<<dim3(64, 4, 3), dim3(512), 0, stream>>>(
        q, k, v, nullptr, wb, Qh, Kh, VhT, nullptr);

    attn_mfma<<<dim3(32, 8, 2), dim3(512), 0, stream>>>(Qh, Kh, VhT, bits, ctx);

    gemm_mfma<1><<<dim3(64, 4, 1), dim3(512), 0, stream>>>(
        nullptr, nullptr, nullptr, ctx, wb, nullptr, nullptr, nullptr, out);
}